// Round 7
// baseline (277.604 us; speedup 1.0000x reference)
//
#include <hip/hip_runtime.h>

#define NN 100000
#define NE 3200000
#define DD 64
#define KE 128                // edges per worker target (NE % KE == 0)
#define NW (NE / KE)          // 25000 full-wave workers

typedef unsigned int uint32;

// ---------------------------------------------------------------------------
// bf16 round-to-nearest-even of an f32 (inputs finite).
// ---------------------------------------------------------------------------
__device__ inline uint32 bf16_rne(float f) {
    uint32 u = __float_as_uint(f);
    return (u + 0x7fffu + ((u >> 16) & 1u)) >> 16;
}

// ---------------------------------------------------------------------------
// prep: one thread per edge. Inline int64/int32 detection (two hot words).
// Writes packed edge record (bits 31..17 = bf16(val) sans sign, val >= 0;
// bits 16..0 = col) and fills rp[] spans from the sorted row stream:
// thread e writes rp[q] = e+1 for q in (row[e], row[e+1]]; thread 0 also
// fills rp[0..row[0]] = 0; the last edge covers (row[NE-1], NN].
// 32 zero records of padding allow batch overrun (gather row 0, val 0).
// ---------------------------------------------------------------------------
__global__ void prep_kernel(const void* rowbuf, const void* colbuf,
                            const float* __restrict__ val,
                            uint32* __restrict__ erec, int* __restrict__ rp) {
    int e = blockIdx.x * blockDim.x + threadIdx.x;
    if (e >= NE + 32) return;
    if (e >= NE) { erec[e] = 0u; return; }

    const int* p32 = (const int*)rowbuf;
    bool is64 = (p32[NE / 2 + 1] == 0 && p32[NE / 2] != 0);

    int r, rn, c;
    if (is64) {
        const long long* row = (const long long*)rowbuf;
        const long long* col = (const long long*)colbuf;
        r  = (int)row[e];
        rn = (e == NE - 1) ? NN : (int)row[e + 1];
        c  = (int)col[e];
    } else {
        const int* row = (const int*)rowbuf;
        const int* col = (const int*)colbuf;
        r  = row[e];
        rn = (e == NE - 1) ? NN : row[e + 1];
        c  = col[e];
    }
    erec[e] = ((bf16_rne(val[e]) & 0x7fffu) << 17) | (uint32)c;
    for (int q = r + 1; q <= rn; ++q) rp[q] = e + 1;
    if (e == 0) { for (int q = 0; q <= r; ++q) rp[q] = 0; }
}

// ---------------------------------------------------------------------------
// wstart (inverse map): ws[w] = first row r with rp[r] >= KE*w.
// Thread r>=1 writes ws[w] = r for w in [rp[r-1]/KE + 1, rp[r]/KE],
// clamped to NW-1; ws[0] = 0; ws[NW] = NN (trailing empty rows belong to
// the last worker and get zero-flushed in its drain).
// ---------------------------------------------------------------------------
__global__ void wstart_kernel(const int* __restrict__ rp, int* __restrict__ ws) {
    int r = blockIdx.x * blockDim.x + threadIdx.x;
    if (r > NN) return;
    if (r == NN) { ws[NW] = NN; return; }
    if (r == 0)  { ws[0] = 0;   return; }
    int w0 = rp[r - 1] / KE + 1;
    int w1 = rp[r] / KE;
    if (w1 > NW - 1) w1 = NW - 1;
    for (int w = w0; w <= w1; ++w) ws[w] = r;
}

// ---------------------------------------------------------------------------
// f32 -> packed bf16 (uint = 2 features), 8 elements/thread.
// ---------------------------------------------------------------------------
__global__ void cvt_bf16_kernel(const float* __restrict__ X,
                                uint32* __restrict__ Y, int n) {
    int i = (blockIdx.x * blockDim.x + threadIdx.x) * 8;
    if (i >= n) return;
    float4 a = *(const float4*)(X + i);
    float4 b = *(const float4*)(X + i + 4);
    uint4 o;
    o.x = bf16_rne(a.x) | (bf16_rne(a.y) << 16);
    o.y = bf16_rne(a.z) | (bf16_rne(a.w) << 16);
    o.z = bf16_rne(b.x) | (bf16_rne(b.y) << 16);
    o.w = bf16_rne(b.z) | (bf16_rne(b.w) << 16);
    *(uint4*)(Y + i / 2) = o;
}

// ---------------------------------------------------------------------------
// SpMM, full-wave workers with scalar control flow. Worker = one wave64;
// lane l holds feature l. Edge records stream through SGPRs (uniform loads),
// col/val unpack and row-boundary checks are scalar (zero divergence); the
// only per-edge vector work is {address add, bf16 extract, fmac}. 16 gathers
// in flight per wave. Row flush: pair-shfl, pack 2x bf16, even lanes store
// one uint (128 B/row). Overrun edges gather row 0 with val 0 (harmless:
// by then all owned rows are flushed and acc is never stored again).
// ---------------------------------------------------------------------------
#define FLUSH_ROW() {                                                   \
    float oth_ = __shfl(acc, lane ^ 1, 64);                             \
    if (!(lane & 1)) {                                                  \
        uint32 pk_ = bf16_rne(acc) | (bf16_rne(oth_) << 16);            \
        ob[(size_t)rr * 32 + half] = pk_;                               \
    }                                                                   \
    acc = 0.f; ++rr; }

#define ACCE(I) {                                                       \
    while (e + (I) >= re && rr < r1) {                                  \
        FLUSH_ROW();                                                    \
        re = (rr < r1) ? __builtin_amdgcn_readfirstlane(rp[rr + 1])     \
                       : 0x7fffffff;                                    \
    }                                                                   \
    float v_ = __uint_as_float((rec[I] >> 17) << 16);                   \
    float f_ = __uint_as_float((g[I] << lsh) & 0xffff0000u);            \
    acc = fmaf(v_, f_, acc); }

__global__ __launch_bounds__(256) void spmm_kernel(
    const uint32* __restrict__ Xq, const uint32* __restrict__ erec,
    const int* __restrict__ rp, const int* __restrict__ ws,
    uint32* __restrict__ ob) {
    int wid  = (blockIdx.x * blockDim.x + threadIdx.x) >> 6;
    int lane = threadIdx.x & 63;
    int w = __builtin_amdgcn_readfirstlane(wid);
    if (w >= NW) return;

    int r0 = __builtin_amdgcn_readfirstlane(ws[w]);
    int r1 = __builtin_amdgcn_readfirstlane(ws[w + 1]);
    if (r0 >= r1) return;

    int rr = r0;
    int e  = __builtin_amdgcn_readfirstlane(rp[r0]);
    int ee = __builtin_amdgcn_readfirstlane(rp[r1]);
    int re = __builtin_amdgcn_readfirstlane(rp[r0 + 1]);

    float  acc  = 0.f;
    int    half = lane >> 1;                 // uint index within a row
    uint32 lsh  = (lane & 1) ? 0u : 16u;     // select lo/hi bf16

    for (; e < ee; e += 16) {
        uint32 rec[16];
#pragma unroll
        for (int i = 0; i < 16; ++i)
            rec[i] = (uint32)__builtin_amdgcn_readfirstlane((int)erec[e + i]);
        uint32 g[16];
#pragma unroll
        for (int i = 0; i < 16; ++i)
            g[i] = Xq[(size_t)(rec[i] & 0x1ffffu) * 32u + (uint32)half];
        ACCE(0)  ACCE(1)  ACCE(2)  ACCE(3)
        ACCE(4)  ACCE(5)  ACCE(6)  ACCE(7)
        ACCE(8)  ACCE(9)  ACCE(10) ACCE(11)
        ACCE(12) ACCE(13) ACCE(14) ACCE(15)
    }
    // drain: store last row's acc, then zeros for trailing empty rows
    while (rr < r1) FLUSH_ROW();
}

// ---------------------------------------------------------------------------
// Dense per-node GEMM on packed-bf16 input:
//   y[row,:] = act(unpack(Bb[row,:]) @ W + b)
// One thread per node, 64 f32 accumulators, W staged in LDS as float4
// (uniform-address broadcast, conflict-free).
// ---------------------------------------------------------------------------
template <bool OUT_BF16>
__global__ __launch_bounds__(256) void gemm_kernel(
    const uint32* __restrict__ Bb, const float* __restrict__ W,
    const float* __restrict__ bias, void* __restrict__ outv, int leaky) {
    __shared__ float4 sW[DD * 16];   // sW[k*16 + j4] = W[k][4j4 .. 4j4+3]
    __shared__ float  sb[DD];
    for (int i = threadIdx.x; i < DD * 16; i += 256)
        sW[i] = ((const float4*)W)[i];
    if (threadIdx.x < DD) sb[threadIdx.x] = bias[threadIdx.x];
    __syncthreads();

    int row = blockIdx.x * 256 + threadIdx.x;
    if (row >= NN) return;

    float acc[DD];
#pragma unroll
    for (int j = 0; j < DD; ++j) acc[j] = sb[j];

    const uint4* Bp = (const uint4*)(Bb + (size_t)row * 32);
#pragma unroll
    for (int q4 = 0; q4 < 8; ++q4) {
        uint4 u4 = Bp[q4];
        uint32 us[4] = {u4.x, u4.y, u4.z, u4.w};
#pragma unroll
        for (int t = 0; t < 4; ++t) {
            int k = q4 * 8 + t * 2;
            float x0 = __uint_as_float(us[t] << 16);
            float x1 = __uint_as_float(us[t] & 0xffff0000u);
#pragma unroll
            for (int j4 = 0; j4 < 16; ++j4) {
                float4 w0 = sW[k * 16 + j4];
                float4 w1 = sW[(k + 1) * 16 + j4];
                acc[4 * j4 + 0] = fmaf(x0, w0.x, acc[4 * j4 + 0]);
                acc[4 * j4 + 1] = fmaf(x0, w0.y, acc[4 * j4 + 1]);
                acc[4 * j4 + 2] = fmaf(x0, w0.z, acc[4 * j4 + 2]);
                acc[4 * j4 + 3] = fmaf(x0, w0.w, acc[4 * j4 + 3]);
                acc[4 * j4 + 0] = fmaf(x1, w1.x, acc[4 * j4 + 0]);
                acc[4 * j4 + 1] = fmaf(x1, w1.y, acc[4 * j4 + 1]);
                acc[4 * j4 + 2] = fmaf(x1, w1.z, acc[4 * j4 + 2]);
                acc[4 * j4 + 3] = fmaf(x1, w1.w, acc[4 * j4 + 3]);
            }
        }
    }

    if (leaky) {
#pragma unroll
        for (int j = 0; j < DD; ++j)
            acc[j] = (acc[j] >= 0.f) ? acc[j] : 0.2f * acc[j];
    }

    if (OUT_BF16) {
        uint32* o = (uint32*)outv + (size_t)row * 32;
#pragma unroll
        for (int q = 0; q < 32; ++q)
            o[q] = bf16_rne(acc[2 * q]) | (bf16_rne(acc[2 * q + 1]) << 16);
    } else {
        float* o = (float*)outv + (size_t)row * DD;
#pragma unroll
        for (int j = 0; j < DD; ++j) o[j] = acc[j];
    }
}

// ---------------------------------------------------------------------------
extern "C" void kernel_launch(void* const* d_in, const int* in_sizes, int n_in,
                              void* d_out, int out_size, void* d_ws, size_t ws_size,
                              hipStream_t stream) {
    const float* x       = (const float*)d_in[0];
    const void*  adj_row = d_in[1];
    const void*  adj_col = d_in[2];
    const float* adj_val = (const float*)d_in[3];
    const float* W1      = (const float*)d_in[4];
    const float* b1      = (const float*)d_in[5];
    const float* W2      = (const float*)d_in[6];
    const float* b2      = (const float*)d_in[7];
    float*       out     = (float*)d_out;

    // ws: bufA [NN*32 u32] | bufB [NN*32 u32] | erec [NE+32 u32] | rp | ws
    uint32* bufA = (uint32*)d_ws;                    // xb, later hb
    uint32* bufB = bufA + (size_t)NN * 32;           // spmm outputs (packed)
    uint32* erec = bufB + (size_t)NN * 32;
    int*    rp   = (int*)(erec + NE + 32);
    int*    wst  = rp + (NN + 1);

    prep_kernel<<<(NE + 32 + 255) / 256, 256, 0, stream>>>(adj_row, adj_col,
                                                           adj_val, erec, rp);
    wstart_kernel<<<(NN + 1 + 255) / 256, 256, 0, stream>>>(rp, wst);

    const int n = NN * DD;
    cvt_bf16_kernel<<<(n / 8 + 255) / 256, 256, 0, stream>>>(x, bufA, n);

    const int spmm_blocks = NW / 4;            // 6250 (4 waves per block)
    const int gemm_blocks = (NN + 255) / 256;  // 391

    // layer 1: bufB = bf16(A xb) ; bufA = bf16(LReLU(bufB W1 + b1))
    spmm_kernel<<<spmm_blocks, 256, 0, stream>>>(bufA, erec, rp, wst, bufB);
    gemm_kernel<true><<<gemm_blocks, 256, 0, stream>>>(bufB, W1, b1, bufA, 1);

    // layer 2: bufB = bf16(A h) ; out = bufB W2 + b2 (f32)
    spmm_kernel<<<spmm_blocks, 256, 0, stream>>>(bufA, erec, rp, wst, bufB);
    gemm_kernel<false><<<gemm_blocks, 256, 0, stream>>>(bufB, W2, b2, out, 0);
}

// Round 8
// 247.713 us; speedup vs baseline: 1.1207x; 1.1207x over previous
//
#include <hip/hip_runtime.h>

#define NN 100000
#define NE 3200000
#define DD 64
#define KE 64                 // edges per half-wave worker (NE % KE == 0)
#define NW (NE / KE)          // 50000 workers

typedef unsigned int uint32;

// ---------------------------------------------------------------------------
// bf16 round-to-nearest-even of an f32 (inputs finite).
// ---------------------------------------------------------------------------
__device__ inline uint32 bf16_rne(float f) {
    uint32 u = __float_as_uint(f);
    return (u + 0x7fffu + ((u >> 16) & 1u)) >> 16;
}

// ---------------------------------------------------------------------------
// prep: one thread per edge. Inline int64/int32 detection (two hot words).
// Writes packed edge record (bits 31..17 = bf16(val) sans sign, val >= 0;
// bits 16..0 = col) and fills rp[] spans from the sorted row stream:
// thread e writes rp[q] = e+1 for q in (row[e], row[e+1]]; thread 0 also
// fills rp[0..row[0]] = 0; the last edge covers (row[NE-1], NN].
// 32 zero records of padding allow masked batch overrun.
// ---------------------------------------------------------------------------
__global__ void prep_kernel(const void* rowbuf, const void* colbuf,
                            const float* __restrict__ val,
                            uint32* __restrict__ erec, int* __restrict__ rp) {
    int e = blockIdx.x * blockDim.x + threadIdx.x;
    if (e >= NE + 32) return;
    if (e >= NE) { erec[e] = 0u; return; }

    const int* p32 = (const int*)rowbuf;
    bool is64 = (p32[NE / 2 + 1] == 0 && p32[NE / 2] != 0);

    int r, rn, c;
    if (is64) {
        const long long* row = (const long long*)rowbuf;
        const long long* col = (const long long*)colbuf;
        r  = (int)row[e];
        rn = (e == NE - 1) ? NN : (int)row[e + 1];
        c  = (int)col[e];
    } else {
        const int* row = (const int*)rowbuf;
        const int* col = (const int*)colbuf;
        r  = row[e];
        rn = (e == NE - 1) ? NN : row[e + 1];
        c  = col[e];
    }
    erec[e] = ((bf16_rne(val[e]) & 0x7fffu) << 17) | (uint32)c;
    for (int q = r + 1; q <= rn; ++q) rp[q] = e + 1;
    if (e == 0) { for (int q = 0; q <= r; ++q) rp[q] = 0; }
}

// ---------------------------------------------------------------------------
// wstart (inverse map): ws[w] = first row r with rp[r] >= KE*w.
// Thread r>=1 writes ws[w] = r for w in [rp[r-1]/KE + 1, rp[r]/KE],
// clamped to NW-1; ws[0] = 0; ws[NW] = NN.
// ---------------------------------------------------------------------------
__global__ void wstart_kernel(const int* __restrict__ rp, int* __restrict__ ws) {
    int r = blockIdx.x * blockDim.x + threadIdx.x;
    if (r > NN) return;
    if (r == NN) { ws[NW] = NN; return; }
    if (r == 0)  { ws[0] = 0;   return; }
    int w0 = rp[r - 1] / KE + 1;
    int w1 = rp[r] / KE;
    if (w1 > NW - 1) w1 = NW - 1;
    for (int w = w0; w <= w1; ++w) ws[w] = r;
}

// ---------------------------------------------------------------------------
// f32 -> packed bf16 (uint = 2 features), 8 elements/thread.
// ---------------------------------------------------------------------------
__global__ void cvt_bf16_kernel(const float* __restrict__ X,
                                uint32* __restrict__ Y, int n) {
    int i = (blockIdx.x * blockDim.x + threadIdx.x) * 8;
    if (i >= n) return;
    float4 a = *(const float4*)(X + i);
    float4 b = *(const float4*)(X + i + 4);
    uint4 o;
    o.x = bf16_rne(a.x) | (bf16_rne(a.y) << 16);
    o.y = bf16_rne(a.z) | (bf16_rne(a.w) << 16);
    o.z = bf16_rne(b.x) | (bf16_rne(b.y) << 16);
    o.w = bf16_rne(b.z) | (bf16_rne(b.w) << 16);
    *(uint4*)(Y + i / 2) = o;
}

// ---------------------------------------------------------------------------
// SpMM with exclusive row ownership. Half-wave (32 lanes) worker streams its
// edge range in 32-edge batches with a 16-deep gather pipeline. Lane sl holds
// features {2sl, 2sl+1}. On row boundary the accumulated row is stored ONCE
// as packed bf16 (no atomics, no pre-zero; drain also emits empty rows).
// Batch-overrun edges are MASKED to record 0 (val = 0, col = 0): their
// gathers hit the single L1-hot row-0 line instead of random junk lines
// (round 6's extra ~80 MB FETCH).
// ---------------------------------------------------------------------------
#define ISSUE(G, I) {                                           \
    uint32 t_ = (uint32)__shfl((int)rw, (I), 32);               \
    G = Xq[(size_t)(t_ & 0x1ffffu) * 32u + (uint32)sl]; }

#define ACCUM(G, I) {                                           \
    uint32 t_ = (uint32)__shfl((int)rw, (I), 32);               \
    while (rr < r1 && e0 + (I) >= re) {                         \
        ob[(size_t)rr * 32 + sl] =                              \
            bf16_rne(ax) | (bf16_rne(ay) << 16);                \
        ax = 0.f; ay = 0.f; ++rr;                               \
        int nxt_ = rr + 1; if (nxt_ > NN) nxt_ = NN;            \
        re = rp[nxt_];                                          \
    }                                                           \
    float vi_ = __uint_as_float((t_ >> 17) << 16);              \
    float lo_ = __uint_as_float(G << 16);                       \
    float hi_ = __uint_as_float(G & 0xffff0000u);               \
    ax = fmaf(vi_, lo_, ax); ay = fmaf(vi_, hi_, ay); }

__global__ __launch_bounds__(256) void spmm_kernel(
    const uint32* __restrict__ Xq, const uint32* __restrict__ erec,
    const int* __restrict__ rp, const int* __restrict__ ws,
    uint32* __restrict__ ob) {
    int worker = (blockIdx.x * blockDim.x + threadIdx.x) >> 5;
    int sl = threadIdx.x & 31;
    if (worker >= NW) return;

    int rr = ws[worker];
    int r1 = ws[worker + 1];
    if (rr >= r1) return;

    int eb = rp[rr];
    int ee = rp[r1];
    int re = rp[rr + 1];
    float ax = 0.f, ay = 0.f;

    for (int e0 = eb; e0 < ee; e0 += 32) {
        uint32 rw = erec[e0 + sl];           // padded: always in-bounds
        rw = (e0 + sl < ee) ? rw : 0u;       // mask overrun -> row 0, val 0
        uint32 g0, g1, g2, g3, g4, g5, g6, g7;
        uint32 h0, h1, h2, h3, h4, h5, h6, h7;
        ISSUE(g0, 0)  ISSUE(g1, 1)  ISSUE(g2, 2)  ISSUE(g3, 3)
        ISSUE(g4, 4)  ISSUE(g5, 5)  ISSUE(g6, 6)  ISSUE(g7, 7)
        ISSUE(h0, 8)  ISSUE(h1, 9)  ISSUE(h2, 10) ISSUE(h3, 11)
        ISSUE(h4, 12) ISSUE(h5, 13) ISSUE(h6, 14) ISSUE(h7, 15)
        ACCUM(g0, 0)  ACCUM(g1, 1)  ACCUM(g2, 2)  ACCUM(g3, 3)
        ACCUM(g4, 4)  ACCUM(g5, 5)  ACCUM(g6, 6)  ACCUM(g7, 7)
        ISSUE(g0, 16) ISSUE(g1, 17) ISSUE(g2, 18) ISSUE(g3, 19)
        ISSUE(g4, 20) ISSUE(g5, 21) ISSUE(g6, 22) ISSUE(g7, 23)
        ACCUM(h0, 8)  ACCUM(h1, 9)  ACCUM(h2, 10) ACCUM(h3, 11)
        ACCUM(h4, 12) ACCUM(h5, 13) ACCUM(h6, 14) ACCUM(h7, 15)
        ISSUE(h0, 24) ISSUE(h1, 25) ISSUE(h2, 26) ISSUE(h3, 27)
        ISSUE(h4, 28) ISSUE(h5, 29) ISSUE(h6, 30) ISSUE(h7, 31)
        ACCUM(g0, 16) ACCUM(g1, 17) ACCUM(g2, 18) ACCUM(g3, 19)
        ACCUM(g4, 20) ACCUM(g5, 21) ACCUM(g6, 22) ACCUM(g7, 23)
        ACCUM(h0, 24) ACCUM(h1, 25) ACCUM(h2, 26) ACCUM(h3, 27)
        ACCUM(h4, 28) ACCUM(h5, 29) ACCUM(h6, 30) ACCUM(h7, 31)
    }
    // drain: last row + trailing empty rows
    while (rr < r1) {
        ob[(size_t)rr * 32 + sl] = bf16_rne(ax) | (bf16_rne(ay) << 16);
        ax = 0.f; ay = 0.f; ++rr;
    }
}

// ---------------------------------------------------------------------------
// Dense per-node GEMM on packed-bf16 input:
//   y[row,:] = act(unpack(Bb[row,:]) @ W + b)
// One thread per node, 64 f32 accumulators, W staged in LDS as float4
// (uniform-address broadcast, conflict-free).
// ---------------------------------------------------------------------------
template <bool OUT_BF16>
__global__ __launch_bounds__(256) void gemm_kernel(
    const uint32* __restrict__ Bb, const float* __restrict__ W,
    const float* __restrict__ bias, void* __restrict__ outv, int leaky) {
    __shared__ float4 sW[DD * 16];   // sW[k*16 + j4] = W[k][4j4 .. 4j4+3]
    __shared__ float  sb[DD];
    for (int i = threadIdx.x; i < DD * 16; i += 256)
        sW[i] = ((const float4*)W)[i];
    if (threadIdx.x < DD) sb[threadIdx.x] = bias[threadIdx.x];
    __syncthreads();

    int row = blockIdx.x * 256 + threadIdx.x;
    if (row >= NN) return;

    float acc[DD];
#pragma unroll
    for (int j = 0; j < DD; ++j) acc[j] = sb[j];

    const uint4* Bp = (const uint4*)(Bb + (size_t)row * 32);
#pragma unroll
    for (int q4 = 0; q4 < 8; ++q4) {
        uint4 u4 = Bp[q4];
        uint32 us[4] = {u4.x, u4.y, u4.z, u4.w};
#pragma unroll
        for (int t = 0; t < 4; ++t) {
            int k = q4 * 8 + t * 2;
            float x0 = __uint_as_float(us[t] << 16);
            float x1 = __uint_as_float(us[t] & 0xffff0000u);
#pragma unroll
            for (int j4 = 0; j4 < 16; ++j4) {
                float4 w0 = sW[k * 16 + j4];
                float4 w1 = sW[(k + 1) * 16 + j4];
                acc[4 * j4 + 0] = fmaf(x0, w0.x, acc[4 * j4 + 0]);
                acc[4 * j4 + 1] = fmaf(x0, w0.y, acc[4 * j4 + 1]);
                acc[4 * j4 + 2] = fmaf(x0, w0.z, acc[4 * j4 + 2]);
                acc[4 * j4 + 3] = fmaf(x0, w0.w, acc[4 * j4 + 3]);
                acc[4 * j4 + 0] = fmaf(x1, w1.x, acc[4 * j4 + 0]);
                acc[4 * j4 + 1] = fmaf(x1, w1.y, acc[4 * j4 + 1]);
                acc[4 * j4 + 2] = fmaf(x1, w1.z, acc[4 * j4 + 2]);
                acc[4 * j4 + 3] = fmaf(x1, w1.w, acc[4 * j4 + 3]);
            }
        }
    }

    if (leaky) {
#pragma unroll
        for (int j = 0; j < DD; ++j)
            acc[j] = (acc[j] >= 0.f) ? acc[j] : 0.2f * acc[j];
    }

    if (OUT_BF16) {
        uint32* o = (uint32*)outv + (size_t)row * 32;
#pragma unroll
        for (int q = 0; q < 32; ++q)
            o[q] = bf16_rne(acc[2 * q]) | (bf16_rne(acc[2 * q + 1]) << 16);
    } else {
        float* o = (float*)outv + (size_t)row * DD;
#pragma unroll
        for (int j = 0; j < DD; ++j) o[j] = acc[j];
    }
}

// ---------------------------------------------------------------------------
extern "C" void kernel_launch(void* const* d_in, const int* in_sizes, int n_in,
                              void* d_out, int out_size, void* d_ws, size_t ws_size,
                              hipStream_t stream) {
    const float* x       = (const float*)d_in[0];
    const void*  adj_row = d_in[1];
    const void*  adj_col = d_in[2];
    const float* adj_val = (const float*)d_in[3];
    const float* W1      = (const float*)d_in[4];
    const float* b1      = (const float*)d_in[5];
    const float* W2      = (const float*)d_in[6];
    const float* b2      = (const float*)d_in[7];
    float*       out     = (float*)d_out;

    // ws: bufA [NN*32 u32] | bufB [NN*32 u32] | erec [NE+32 u32] | rp | ws
    uint32* bufA = (uint32*)d_ws;                    // xb, later hb
    uint32* bufB = bufA + (size_t)NN * 32;           // spmm outputs (packed)
    uint32* erec = bufB + (size_t)NN * 32;
    int*    rp   = (int*)(erec + NE + 32);
    int*    wst  = rp + (NN + 1);

    prep_kernel<<<(NE + 32 + 255) / 256, 256, 0, stream>>>(adj_row, adj_col,
                                                           adj_val, erec, rp);
    wstart_kernel<<<(NN + 1 + 255) / 256, 256, 0, stream>>>(rp, wst);

    const int n = NN * DD;
    cvt_bf16_kernel<<<(n / 8 + 255) / 256, 256, 0, stream>>>(x, bufA, n);

    const int spmm_blocks = (NW * 32) / 256;   // 6250
    const int gemm_blocks = (NN + 255) / 256;  // 391

    // layer 1: bufB = bf16(A xb) ; bufA = bf16(LReLU(bufB W1 + b1))
    spmm_kernel<<<spmm_blocks, 256, 0, stream>>>(bufA, erec, rp, wst, bufB);
    gemm_kernel<true><<<gemm_blocks, 256, 0, stream>>>(bufB, W1, b1, bufA, 1);

    // layer 2: bufB = bf16(A h) ; out = bufB W2 + b2 (f32)
    spmm_kernel<<<spmm_blocks, 256, 0, stream>>>(bufA, erec, rp, wst, bufB);
    gemm_kernel<false><<<gemm_blocks, 256, 0, stream>>>(bufB, W2, b2, out, 0);
}

// Round 9
// 237.739 us; speedup vs baseline: 1.1677x; 1.0420x over previous
//
#include <hip/hip_runtime.h>

#define NN 100000
#define NE 3200000
#define DD 64
#define KE 64                 // edges per half-wave worker (NE % KE == 0)
#define NW (NE / KE)          // 50000 workers

typedef unsigned int uint32;

// ---------------------------------------------------------------------------
// bf16 round-to-nearest-even of an f32 (inputs finite).
// ---------------------------------------------------------------------------
__device__ inline uint32 bf16_rne(float f) {
    uint32 u = __float_as_uint(f);
    return (u + 0x7fffu + ((u >> 16) & 1u)) >> 16;
}

// ---------------------------------------------------------------------------
// prep: one thread per edge. Inline int64/int32 detection (two hot words).
// Writes packed edge record (bits 31..17 = bf16(val) sans sign, val >= 0;
// bits 16..0 = col) and fills rp[] spans from the sorted row stream.
// Worker-start table fused in: at each KE boundary, ws[(e+1)/KE] =
// row[e] + 1 == lower_bound(rp, KE*w) for both split and non-split rows
// (rows (row[e], row[e+1]] all have rp == e+1; no r <= row[e] can reach it).
// 32 zero records of padding allow masked batch overrun.
// ---------------------------------------------------------------------------
__global__ void prep_kernel(const void* rowbuf, const void* colbuf,
                            const float* __restrict__ val,
                            uint32* __restrict__ erec, int* __restrict__ rp,
                            int* __restrict__ ws) {
    int e = blockIdx.x * blockDim.x + threadIdx.x;
    if (e >= NE + 32) return;
    if (e >= NE) { erec[e] = 0u; return; }

    const int* p32 = (const int*)rowbuf;
    bool is64 = (p32[NE / 2 + 1] == 0 && p32[NE / 2] != 0);

    int r, rn, c;
    if (is64) {
        const long long* row = (const long long*)rowbuf;
        const long long* col = (const long long*)colbuf;
        r  = (int)row[e];
        rn = (e == NE - 1) ? NN : (int)row[e + 1];
        c  = (int)col[e];
    } else {
        const int* row = (const int*)rowbuf;
        const int* col = (const int*)colbuf;
        r  = row[e];
        rn = (e == NE - 1) ? NN : row[e + 1];
        c  = col[e];
    }
    erec[e] = ((bf16_rne(val[e]) & 0x7fffu) << 17) | (uint32)c;
    for (int q = r + 1; q <= rn; ++q) rp[q] = e + 1;
    if (e == 0) {
        for (int q = 0; q <= r; ++q) rp[q] = 0;
        ws[0]  = 0;
        ws[NW] = NN;
    }
    if (((e + 1) & (KE - 1)) == 0 && (e + 1) < NE)
        ws[(e + 1) / KE] = r + 1;
}

// ---------------------------------------------------------------------------
// f32 -> packed bf16 (uint = 2 features), 8 elements/thread.
// ---------------------------------------------------------------------------
__global__ void cvt_bf16_kernel(const float* __restrict__ X,
                                uint32* __restrict__ Y, int n) {
    int i = (blockIdx.x * blockDim.x + threadIdx.x) * 8;
    if (i >= n) return;
    float4 a = *(const float4*)(X + i);
    float4 b = *(const float4*)(X + i + 4);
    uint4 o;
    o.x = bf16_rne(a.x) | (bf16_rne(a.y) << 16);
    o.y = bf16_rne(a.z) | (bf16_rne(a.w) << 16);
    o.z = bf16_rne(b.x) | (bf16_rne(b.y) << 16);
    o.w = bf16_rne(b.z) | (bf16_rne(b.w) << 16);
    *(uint4*)(Y + i / 2) = o;
}

// ---------------------------------------------------------------------------
// SpMM with exclusive row ownership. Half-wave (32 lanes) worker streams its
// edge range in 32-edge batches with a 16-deep gather pipeline. Lane sl holds
// features {2sl, 2sl+1}. The shfl'd edge record is saved at ISSUE time (u/w
// named regs) and reused at ACCUM -- one ds op per edge instead of two. The
// flush check is a single compare: re becomes INT_MAX once the last owned
// row is flushed. Rows are stored ONCE as packed bf16 (no atomics, no
// pre-zero; drain also emits empty rows). Batch-overrun edges are masked to
// record 0 (row 0, val 0: one L1-hot line).
// ---------------------------------------------------------------------------
#define ISSUE(G, U, I) {                                        \
    U = (uint32)__shfl((int)rw, (I), 32);                       \
    G = Xq[(size_t)(U & 0x1ffffu) * 32u + (uint32)sl]; }

#define ACCUM(G, U, I) {                                        \
    while (e0 + (I) >= re) {                                    \
        ob[(size_t)rr * 32 + sl] =                              \
            bf16_rne(ax) | (bf16_rne(ay) << 16);                \
        ax = 0.f; ay = 0.f; ++rr;                               \
        re = (rr < r1) ? rp[rr + 1] : 0x7fffffff;               \
    }                                                           \
    float vi_ = __uint_as_float((U >> 17) << 16);               \
    float lo_ = __uint_as_float(G << 16);                       \
    float hi_ = __uint_as_float(G & 0xffff0000u);               \
    ax = fmaf(vi_, lo_, ax); ay = fmaf(vi_, hi_, ay); }

__global__ __launch_bounds__(256) void spmm_kernel(
    const uint32* __restrict__ Xq, const uint32* __restrict__ erec,
    const int* __restrict__ rp, const int* __restrict__ ws,
    uint32* __restrict__ ob) {
    int worker = (blockIdx.x * blockDim.x + threadIdx.x) >> 5;
    int sl = threadIdx.x & 31;
    if (worker >= NW) return;

    int rr = ws[worker];
    int r1 = ws[worker + 1];
    if (rr >= r1) return;

    int eb = rp[rr];
    int ee = rp[r1];
    int re = rp[rr + 1];
    float ax = 0.f, ay = 0.f;

    for (int e0 = eb; e0 < ee; e0 += 32) {
        uint32 rw = erec[e0 + sl];           // padded: always in-bounds
        rw = (e0 + sl < ee) ? rw : 0u;       // mask overrun -> row 0, val 0
        uint32 g0, g1, g2, g3, g4, g5, g6, g7;
        uint32 h0, h1, h2, h3, h4, h5, h6, h7;
        uint32 u0, u1, u2, u3, u4, u5, u6, u7;
        uint32 w0, w1, w2, w3, w4, w5, w6, w7;
        ISSUE(g0, u0, 0)  ISSUE(g1, u1, 1)  ISSUE(g2, u2, 2)  ISSUE(g3, u3, 3)
        ISSUE(g4, u4, 4)  ISSUE(g5, u5, 5)  ISSUE(g6, u6, 6)  ISSUE(g7, u7, 7)
        ISSUE(h0, w0, 8)  ISSUE(h1, w1, 9)  ISSUE(h2, w2, 10) ISSUE(h3, w3, 11)
        ISSUE(h4, w4, 12) ISSUE(h5, w5, 13) ISSUE(h6, w6, 14) ISSUE(h7, w7, 15)
        ACCUM(g0, u0, 0)  ACCUM(g1, u1, 1)  ACCUM(g2, u2, 2)  ACCUM(g3, u3, 3)
        ACCUM(g4, u4, 4)  ACCUM(g5, u5, 5)  ACCUM(g6, u6, 6)  ACCUM(g7, u7, 7)
        ISSUE(g0, u0, 16) ISSUE(g1, u1, 17) ISSUE(g2, u2, 18) ISSUE(g3, u3, 19)
        ISSUE(g4, u4, 20) ISSUE(g5, u5, 21) ISSUE(g6, u6, 22) ISSUE(g7, u7, 23)
        ACCUM(h0, w0, 8)  ACCUM(h1, w1, 9)  ACCUM(h2, w2, 10) ACCUM(h3, w3, 11)
        ACCUM(h4, w4, 12) ACCUM(h5, w5, 13) ACCUM(h6, w6, 14) ACCUM(h7, w7, 15)
        ISSUE(h0, w0, 24) ISSUE(h1, w1, 25) ISSUE(h2, w2, 26) ISSUE(h3, w3, 27)
        ISSUE(h4, w4, 28) ISSUE(h5, w5, 29) ISSUE(h6, w6, 30) ISSUE(h7, w7, 31)
        ACCUM(g0, u0, 16) ACCUM(g1, u1, 17) ACCUM(g2, u2, 18) ACCUM(g3, u3, 19)
        ACCUM(g4, u4, 20) ACCUM(g5, u5, 21) ACCUM(g6, u6, 22) ACCUM(g7, u7, 23)
        ACCUM(h0, w0, 24) ACCUM(h1, w1, 25) ACCUM(h2, w2, 26) ACCUM(h3, w3, 27)
        ACCUM(h4, w4, 28) ACCUM(h5, w5, 29) ACCUM(h6, w6, 30) ACCUM(h7, w7, 31)
    }
    // drain: last row + trailing empty rows
    while (rr < r1) {
        ob[(size_t)rr * 32 + sl] = bf16_rne(ax) | (bf16_rne(ay) << 16);
        ax = 0.f; ay = 0.f; ++rr;
    }
}

// ---------------------------------------------------------------------------
// Dense per-node GEMM on packed-bf16 input:
//   y[row,:] = act(unpack(Bb[row,:]) @ W + b)
// One thread per node, 64 f32 accumulators, W staged in LDS as float4
// (uniform-address broadcast, conflict-free).
// ---------------------------------------------------------------------------
template <bool OUT_BF16>
__global__ __launch_bounds__(256) void gemm_kernel(
    const uint32* __restrict__ Bb, const float* __restrict__ W,
    const float* __restrict__ bias, void* __restrict__ outv, int leaky) {
    __shared__ float4 sW[DD * 16];   // sW[k*16 + j4] = W[k][4j4 .. 4j4+3]
    __shared__ float  sb[DD];
    for (int i = threadIdx.x; i < DD * 16; i += 256)
        sW[i] = ((const float4*)W)[i];
    if (threadIdx.x < DD) sb[threadIdx.x] = bias[threadIdx.x];
    __syncthreads();

    int row = blockIdx.x * 256 + threadIdx.x;
    if (row >= NN) return;

    float acc[DD];
#pragma unroll
    for (int j = 0; j < DD; ++j) acc[j] = sb[j];

    const uint4* Bp = (const uint4*)(Bb + (size_t)row * 32);
#pragma unroll
    for (int q4 = 0; q4 < 8; ++q4) {
        uint4 u4 = Bp[q4];
        uint32 us[4] = {u4.x, u4.y, u4.z, u4.w};
#pragma unroll
        for (int t = 0; t < 4; ++t) {
            int k = q4 * 8 + t * 2;
            float x0 = __uint_as_float(us[t] << 16);
            float x1 = __uint_as_float(us[t] & 0xffff0000u);
#pragma unroll
            for (int j4 = 0; j4 < 16; ++j4) {
                float4 w0 = sW[k * 16 + j4];
                float4 w1 = sW[(k + 1) * 16 + j4];
                acc[4 * j4 + 0] = fmaf(x0, w0.x, acc[4 * j4 + 0]);
                acc[4 * j4 + 1] = fmaf(x0, w0.y, acc[4 * j4 + 1]);
                acc[4 * j4 + 2] = fmaf(x0, w0.z, acc[4 * j4 + 2]);
                acc[4 * j4 + 3] = fmaf(x0, w0.w, acc[4 * j4 + 3]);
                acc[4 * j4 + 0] = fmaf(x1, w1.x, acc[4 * j4 + 0]);
                acc[4 * j4 + 1] = fmaf(x1, w1.y, acc[4 * j4 + 1]);
                acc[4 * j4 + 2] = fmaf(x1, w1.z, acc[4 * j4 + 2]);
                acc[4 * j4 + 3] = fmaf(x1, w1.w, acc[4 * j4 + 3]);
            }
        }
    }

    if (leaky) {
#pragma unroll
        for (int j = 0; j < DD; ++j)
            acc[j] = (acc[j] >= 0.f) ? acc[j] : 0.2f * acc[j];
    }

    if (OUT_BF16) {
        uint32* o = (uint32*)outv + (size_t)row * 32;
#pragma unroll
        for (int q = 0; q < 32; ++q)
            o[q] = bf16_rne(acc[2 * q]) | (bf16_rne(acc[2 * q + 1]) << 16);
    } else {
        float* o = (float*)outv + (size_t)row * DD;
#pragma unroll
        for (int j = 0; j < DD; ++j) o[j] = acc[j];
    }
}

// ---------------------------------------------------------------------------
extern "C" void kernel_launch(void* const* d_in, const int* in_sizes, int n_in,
                              void* d_out, int out_size, void* d_ws, size_t ws_size,
                              hipStream_t stream) {
    const float* x       = (const float*)d_in[0];
    const void*  adj_row = d_in[1];
    const void*  adj_col = d_in[2];
    const float* adj_val = (const float*)d_in[3];
    const float* W1      = (const float*)d_in[4];
    const float* b1      = (const float*)d_in[5];
    const float* W2      = (const float*)d_in[6];
    const float* b2      = (const float*)d_in[7];
    float*       out     = (float*)d_out;

    // ws: bufA [NN*32 u32] | bufB [NN*32 u32] | erec [NE+32 u32] | rp | ws
    uint32* bufA = (uint32*)d_ws;                    // xb, later hb
    uint32* bufB = bufA + (size_t)NN * 32;           // spmm outputs (packed)
    uint32* erec = bufB + (size_t)NN * 32;
    int*    rp   = (int*)(erec + NE + 32);
    int*    wst  = rp + (NN + 1);

    prep_kernel<<<(NE + 32 + 255) / 256, 256, 0, stream>>>(adj_row, adj_col,
                                                           adj_val, erec, rp,
                                                           wst);
    const int n = NN * DD;
    cvt_bf16_kernel<<<(n / 8 + 255) / 256, 256, 0, stream>>>(x, bufA, n);

    const int spmm_blocks = (NW * 32) / 256;   // 6250
    const int gemm_blocks = (NN + 255) / 256;  // 391

    // layer 1: bufB = bf16(A xb) ; bufA = bf16(LReLU(bufB W1 + b1))
    spmm_kernel<<<spmm_blocks, 256, 0, stream>>>(bufA, erec, rp, wst, bufB);
    gemm_kernel<true><<<gemm_blocks, 256, 0, stream>>>(bufB, W1, b1, bufA, 1);

    // layer 2: bufB = bf16(A h) ; out = bufB W2 + b2 (f32)
    spmm_kernel<<<spmm_blocks, 256, 0, stream>>>(bufA, erec, rp, wst, bufB);
    gemm_kernel<false><<<gemm_blocks, 256, 0, stream>>>(bufB, W2, b2, out, 0);
}